// Round 1
// baseline (3279.823 us; speedup 1.0000x reference)
//
#include <hip/hip_runtime.h>
#include <hip/hip_bf16.h>

#define Bq 16
#define Tq 256
#define Vq 18000
#define NSq 30
#define Lq 10
#define Gq 3
#define Hq 400
#define Nq (NSq * Bq)      // 480
#define H3q (3 * Hq)       // 1200
#define NKT 25             // 400 / 16 K-tiles
#define NGV 564            // embp col groups (564*32 = 18048 padded cols)
#define NGW 38             // weight col groups (1216 padded cols)
#define NGH 15             // h row groups (480 rows)

typedef __bf16 bf16;
typedef __bf16 bf16x4 __attribute__((ext_vector_type(4)));
typedef __bf16 bf16x8 __attribute__((ext_vector_type(8)));
typedef float floatx16 __attribute__((ext_vector_type(16)));

// ---------------------------------------------------------------------------
// K-1: f32 -> bf16 conversion (vectorized by 4). Used for enc only.
// ---------------------------------------------------------------------------
__global__ __launch_bounds__(256) void k_f2b4(
    const float* __restrict__ src, bf16* __restrict__ dst, const int n4)
{
    int i = blockIdx.x * 256 + threadIdx.x;
    if (i >= n4) return;
    const float4 v = ((const float4*)src)[i];
    bf16x4 o;
    o[0] = (bf16)v.x; o[1] = (bf16)v.y; o[2] = (bf16)v.z; o[3] = (bf16)v.w;
    ((bf16x4*)dst)[i] = o;
}

// ---------------------------------------------------------------------------
// Pack a row-major f32 [nrows][400] matrix into MFMA fragment-major bf16:
// frag f = ((g*25 + kt)*64 + lane), elem j:
//   src(row = g*32 + (lane&31), k = kt*16 + (lane>>5)*8 + j)
// so GEMM loads become lane-contiguous 16 B (fully coalesced).
// Rows beyond nrows are clamped (consumers guard stores).
// ---------------------------------------------------------------------------
__global__ __launch_bounds__(256) void k_packf(
    const float* __restrict__ src, bf16* __restrict__ dst,
    const int ngroups, const int nrows)
{
    const int i = blockIdx.x * 256 + threadIdx.x;
    if (i >= ngroups * NKT * 64) return;
    const int lane = i & 63;
    const int kt = (i >> 6) % NKT;
    const int g = i / (NKT * 64);
    int row = g * 32 + (lane & 31);
    if (row >= nrows) row = nrows - 1;
    const int k0 = kt * 16 + (lane >> 5) * 8;
    const float* s = src + (size_t)row * Hq + k0;
    const float4 a = *(const float4*)s;
    const float4 c = *(const float4*)(s + 4);
    bf16x8 o;
    o[0] = (bf16)a.x; o[1] = (bf16)a.y; o[2] = (bf16)a.z; o[3] = (bf16)a.w;
    o[4] = (bf16)c.x; o[5] = (bf16)c.y; o[6] = (bf16)c.z; o[7] = (bf16)c.w;
    *(bf16x8*)(dst + (size_t)i * 8) = o;
}

// ---------------------------------------------------------------------------
// Build ALL decoder inputs upfront (teacher forcing: targets known).
// Writes packed xbp (A-fragments for the gi GEMM, groups = step*15+g) and
// linear bf16 xlin (for the switch dot product).
// ---------------------------------------------------------------------------
__global__ __launch_bounds__(256) void k_xball(
    const float* __restrict__ slot_emb, const int* __restrict__ dom,
    const int* __restrict__ slo, const float* __restrict__ emb,
    const int* __restrict__ tgt, bf16* __restrict__ xbp,
    bf16* __restrict__ xlin)
{
    const int i = blockIdx.x * 256 + threadIdx.x;
    if (i >= Lq * NGH * NKT * 64) return;
    const int lane = i & 63;
    const int kt = (i >> 6) % NKT;
    const int gg = i / (NKT * 64);
    const int g = gg % NGH;
    const int s = gg / NGH;
    const int n = g * 32 + (lane & 31);
    const int slot = n >> 4, b = n & (Bq - 1);
    const int k0 = kt * 16 + (lane >> 5) * 8;
    float v[8];
    if (s == 0) {
        const float* p1 = slot_emb + (size_t)dom[slot] * Hq + k0;
        const float* p2 = slot_emb + (size_t)slo[slot] * Hq + k0;
        #pragma unroll
        for (int j = 0; j < 8; ++j) v[j] = p1[j] + p2[j];
    } else {
        const int tv = tgt[(b * NSq + slot) * Lq + (s - 1)];
        const float* p = emb + (size_t)tv * Hq + k0;
        #pragma unroll
        for (int j = 0; j < 8; ++j) v[j] = p[j];
    }
    bf16x8 o;
    #pragma unroll
    for (int j = 0; j < 8; ++j) o[j] = (bf16)v[j];
    *(bf16x8*)(xbp + (size_t)i * 8) = o;
    *(bf16x8*)(xlin + ((size_t)(s * Nq + n)) * Hq + k0) = o;
}

// ---------------------------------------------------------------------------
// Init h (f32 state) and packed hbp from encoded_hidden.
// ---------------------------------------------------------------------------
__global__ __launch_bounds__(256) void k_h0(
    const float* __restrict__ ehid, float* __restrict__ h,
    bf16* __restrict__ hbp)
{
    const int i = blockIdx.x * 256 + threadIdx.x;
    if (i >= NGH * NKT * 64) return;
    const int lane = i & 63;
    const int kt = (i >> 6) % NKT;
    const int g = i / (NKT * 64);
    const int n = g * 32 + (lane & 31);
    const int b = n & (Bq - 1);
    const int k0 = kt * 16 + (lane >> 5) * 8;
    const float* s = ehid + (size_t)b * Hq + k0;
    bf16x8 o;
    #pragma unroll
    for (int j = 0; j < 8; ++j) {
        float v = s[j];
        h[(size_t)n * Hq + k0 + j] = v;
        o[j] = (bf16)v;
    }
    *(bf16x8*)(hbp + (size_t)i * 8) = o;
}

// ---------------------------------------------------------------------------
// gi for ALL 10 steps in one MFMA GEMM: (10*480) x 1200 x 400.
// grid = (38 col tiles, 10 steps); 4 waves x 4 row-group accs = 15 groups.
// All loads coalesced (packed operands).
// ---------------------------------------------------------------------------
__global__ __launch_bounds__(256) void k_gi_all(
    const bf16* __restrict__ xbp, const bf16* __restrict__ wihp,
    float* __restrict__ gi_all)
{
    const int ct = blockIdx.x;
    const int s = blockIdx.y;
    const int wave = threadIdx.x >> 6, lane = threadIdx.x & 63;
    floatx16 acc[4];
    #pragma unroll
    for (int i = 0; i < 4; ++i)
        #pragma unroll
        for (int r = 0; r < 16; ++r) acc[i][r] = 0.f;
    for (int kt = 0; kt < NKT; ++kt) {
        const bf16x8 w = *(const bf16x8*)(wihp + ((size_t)(ct * NKT + kt) * 64 + lane) * 8);
        #pragma unroll
        for (int i = 0; i < 4; ++i) {
            const int g = wave + 4 * i;
            if (g < NGH) {
                const bf16x8 a = *(const bf16x8*)(xbp +
                    ((size_t)((s * NGH + g) * NKT + kt) * 64 + lane) * 8);
                acc[i] = __builtin_amdgcn_mfma_f32_32x32x16_bf16(a, w, acc[i], 0, 0, 0);
            }
        }
    }
    const int j = ct * 32 + (lane & 31);
    if (j >= H3q) return;
    #pragma unroll
    for (int i = 0; i < 4; ++i) {
        const int g = wave + 4 * i;
        if (g < NGH) {
            const int rbase = g * 32 + 4 * (lane >> 5);
            #pragma unroll
            for (int r = 0; r < 16; ++r) {
                const int rr = rbase + (r & 3) + 8 * (r >> 2);
                gi_all[((size_t)(s * Nq + rr)) * H3q + j] = acc[i][r];
            }
        }
    }
}

// ---------------------------------------------------------------------------
// Per-step: gh = h_prev @ W_hh^T (packed operands, coalesced).
// Block (0,0) also zeroes rowsum for this step's vocab epilogue atomics.
// ---------------------------------------------------------------------------
__global__ __launch_bounds__(256) void k_gh(
    const bf16* __restrict__ hbp, const bf16* __restrict__ whhp,
    float* __restrict__ gh, float* __restrict__ rowsum)
{
    if (blockIdx.x == 0 && blockIdx.y == 0) {
        for (int v = threadIdx.x; v < Nq; v += 256) rowsum[v] = 0.f;
    }
    const int ct = blockIdx.x;
    const int wave = threadIdx.x >> 6, lane = threadIdx.x & 63;
    const int g = blockIdx.y * 4 + wave;
    if (g >= NGH) return;
    floatx16 acc;
    #pragma unroll
    for (int r = 0; r < 16; ++r) acc[r] = 0.f;
    for (int kt = 0; kt < NKT; ++kt) {
        const bf16x8 a = *(const bf16x8*)(hbp + ((size_t)(g * NKT + kt) * 64 + lane) * 8);
        const bf16x8 w = *(const bf16x8*)(whhp + ((size_t)(ct * NKT + kt) * 64 + lane) * 8);
        acc = __builtin_amdgcn_mfma_f32_32x32x16_bf16(a, w, acc, 0, 0, 0);
    }
    const int j = ct * 32 + (lane & 31);
    if (j >= H3q) return;
    const int rbase = g * 32 + 4 * (lane >> 5);
    #pragma unroll
    for (int r = 0; r < 16; ++r) {
        const int rr = rbase + (r & 3) + 8 * (r >> 2);
        gh[(size_t)rr * H3q + j] = acc[r];
    }
}

// ---------------------------------------------------------------------------
// GRU nonlinearity + attention + context + switch (+gates at step 0).
// One block per row n. Writes h (f32) and packed hbp. Scores phase is
// wave-cooperative: 50 lanes read one enc row coalesced, butterfly-reduce.
// ---------------------------------------------------------------------------
__global__ __launch_bounds__(256) void k_attn(
    const float* __restrict__ gi_all, const float* __restrict__ gh,
    const float* __restrict__ b_ih, const float* __restrict__ b_hh,
    float* __restrict__ h, bf16* __restrict__ hbp,
    const bf16* __restrict__ xlin, const bf16* __restrict__ encb,
    const int* __restrict__ lens, const float* __restrict__ w_ratio,
    const float* __restrict__ b_ratio, const float* __restrict__ w_gate,
    const float* __restrict__ b_gate, float* __restrict__ prob,
    float* __restrict__ swp, float* __restrict__ out_gates, const int step)
{
    const int n = blockIdx.x;
    const int b = n & (Bq - 1);
    const int tid = threadIdx.x;
    __shared__ float s_h[Hq];
    __shared__ float s_c[Hq];
    __shared__ float s_p[Tq];
    __shared__ float s_red[4];

    const float* gin = gi_all + ((size_t)step * Nq + n) * H3q;
    const float* ghn = gh + (size_t)n * H3q;
    for (int k = tid; k < Hq; k += 256) {
        float ir = gin[k]          + b_ih[k];
        float hr = ghn[k]          + b_hh[k];
        float iz = gin[Hq + k]     + b_ih[Hq + k];
        float hz = ghn[Hq + k]     + b_hh[Hq + k];
        float in_ = gin[2*Hq + k]  + b_ih[2*Hq + k];
        float hn_ = ghn[2*Hq + k]  + b_hh[2*Hq + k];
        float r = 1.f / (1.f + __expf(-(ir + hr)));
        float z = 1.f / (1.f + __expf(-(iz + hz)));
        float nn = tanhf(in_ + r * hn_);
        float hp = h[(size_t)n * Hq + k];
        float hv = (1.f - z) * nn + z * hp;
        s_h[k] = hv;
        h[(size_t)n * Hq + k] = hv;
        hbp[((size_t)(((n >> 5) * NKT + (k >> 4)) * 64
                      + ((k >> 3) & 1) * 32 + (n & 31))) * 8 + (k & 7)] = (bf16)hv;
    }
    __syncthreads();

    // ---- scores: each wave handles 64 t's; 50 lanes x 8 cols, coalesced ----
    const int lane = tid & 63;
    const int wv = tid >> 6;
    float hreg[8];
    #pragma unroll
    for (int j = 0; j < 8; ++j) hreg[j] = 0.f;
    if (lane < 50) {
        #pragma unroll
        for (int j = 0; j < 8; ++j) hreg[j] = s_h[lane * 8 + j];
    }
    for (int it = 0; it < 64; ++it) {
        const int t = wv * 64 + it;
        float part = 0.f;
        if (lane < 50) {
            const bf16x8 e = *(const bf16x8*)(encb + ((size_t)(b * Tq + t)) * Hq + lane * 8);
            #pragma unroll
            for (int j = 0; j < 8; ++j) part += hreg[j] * (float)e[j];
        }
        #pragma unroll
        for (int off = 32; off > 0; off >>= 1) part += __shfl_xor(part, off, 64);
        if (lane == 0) s_p[t] = part;
    }
    __syncthreads();

    const int len = lens[b];
    float score = (tid < len) ? s_p[tid] : -1e9f;
    float mx = score;
    for (int off = 32; off > 0; off >>= 1) mx = fmaxf(mx, __shfl_xor(mx, off, 64));
    if ((tid & 63) == 0) s_red[tid >> 6] = mx;
    __syncthreads();
    mx = fmaxf(fmaxf(s_red[0], s_red[1]), fmaxf(s_red[2], s_red[3]));
    float ev = __expf(score - mx);
    float sm = ev;
    for (int off = 32; off > 0; off >>= 1) sm += __shfl_xor(sm, off, 64);
    __syncthreads();
    if ((tid & 63) == 0) s_red[tid >> 6] = sm;
    __syncthreads();
    sm = s_red[0] + s_red[1] + s_red[2] + s_red[3];
    float p = ev / sm;
    s_p[tid] = p;
    prob[n * Tq + tid] = p;
    __syncthreads();

    // context[k] = sum_t p[t] * enc[b][t][k]  (coalesced across lanes in k)
    for (int k = tid; k < Hq; k += 256) {
        float c = 0.f;
        const bf16* ecol = encb + (size_t)b * Tq * Hq + k;
        for (int tt = 0; tt < Tq; ++tt) c += s_p[tt] * (float)ecol[(size_t)tt * Hq];
        s_c[k] = c;
    }
    __syncthreads();

    const bf16* xr = xlin + ((size_t)step * Nq + n) * Hq;
    float part2 = 0.f;
    for (int k = tid; k < Hq; k += 256) {
        part2 += w_ratio[k]        * s_h[k]
               + w_ratio[Hq + k]   * s_c[k]
               + w_ratio[2*Hq + k] * (float)xr[k];
    }
    for (int off = 32; off > 0; off >>= 1) part2 += __shfl_xor(part2, off, 64);
    __syncthreads();
    if ((tid & 63) == 0) s_red[tid >> 6] = part2;
    __syncthreads();
    if (tid == 0) {
        float tot = s_red[0] + s_red[1] + s_red[2] + s_red[3] + b_ratio[0];
        swp[n] = 1.f / (1.f + __expf(-tot));
    }

    if (step == 0) {
        for (int gg = 0; gg < Gq; ++gg) {
            float pg = 0.f;
            for (int k = tid; k < Hq; k += 256)
                pg += w_gate[gg * Hq + k] * s_c[k];
            for (int off = 32; off > 0; off >>= 1) pg += __shfl_xor(pg, off, 64);
            __syncthreads();
            if ((tid & 63) == 0) s_red[tid >> 6] = pg;
            __syncthreads();
            if (tid == 0)
                out_gates[n * Gq + gg] =
                    s_red[0] + s_red[1] + s_red[2] + s_red[3] + b_gate[gg];
        }
    }
}

// ---------------------------------------------------------------------------
// Vocab GEMM (480 x 18000 x 400), packed operands, 64 cols/block.
// Epilogue: e = exp(logit) stored to eL (max-free softmax; |logit| <~ 15),
// per-row sums reduced via shfl and atomically added to rowsum[480].
// ---------------------------------------------------------------------------
__global__ __launch_bounds__(256, 2) void k_vocab(
    const bf16* __restrict__ hbp, const bf16* __restrict__ embp,
    float* __restrict__ eL, float* __restrict__ rowsum)
{
    const int ct2 = blockIdx.x;           // 0..281 (64 cols each)
    const int wave = threadIdx.x >> 6, lane = threadIdx.x & 63;
    floatx16 acc0[4], acc1[4];
    #pragma unroll
    for (int i = 0; i < 4; ++i)
        #pragma unroll
        for (int r = 0; r < 16; ++r) { acc0[i][r] = 0.f; acc1[i][r] = 0.f; }

    for (int kt = 0; kt < NKT; ++kt) {
        const bf16x8 w0 = *(const bf16x8*)(embp +
            ((size_t)((2 * ct2) * NKT + kt) * 64 + lane) * 8);
        const bf16x8 w1 = *(const bf16x8*)(embp +
            ((size_t)((2 * ct2 + 1) * NKT + kt) * 64 + lane) * 8);
        #pragma unroll
        for (int i = 0; i < 4; ++i) {
            const int g = wave + 4 * i;
            if (g < NGH) {
                const bf16x8 a = *(const bf16x8*)(hbp +
                    ((size_t)(g * NKT + kt) * 64 + lane) * 8);
                acc0[i] = __builtin_amdgcn_mfma_f32_32x32x16_bf16(a, w0, acc0[i], 0, 0, 0);
                acc1[i] = __builtin_amdgcn_mfma_f32_32x32x16_bf16(a, w1, acc1[i], 0, 0, 0);
            }
        }
    }

    const int mcol = lane & 31, half = lane >> 5;
    const int j0 = ct2 * 64 + mcol, j1 = j0 + 32;
    #pragma unroll
    for (int i = 0; i < 4; ++i) {
        const int g = wave + 4 * i;       // wave-uniform -> shfl below is safe
        if (g >= NGH) continue;
        const int rbase = g * 32 + 4 * half;
        #pragma unroll
        for (int r = 0; r < 16; ++r) {
            const int rr = rbase + (r & 3) + 8 * (r >> 2);
            const float e0 = (j0 < Vq) ? __expf(acc0[i][r]) : 0.f;
            const float e1 = (j1 < Vq) ? __expf(acc1[i][r]) : 0.f;
            if (j0 < Vq) eL[(size_t)rr * Vq + j0] = e0;
            if (j1 < Vq) eL[(size_t)rr * Vq + j1] = e1;
            float v = e0 + e1;
            v += __shfl_xor(v, 16, 64);
            v += __shfl_xor(v, 8, 64);
            v += __shfl_xor(v, 4, 64);
            v += __shfl_xor(v, 2, 64);
            v += __shfl_xor(v, 1, 64);
            if (mcol == 0) atomicAdd(&rowsum[rr], v);
        }
    }
}

// ---------------------------------------------------------------------------
// Final: out = e * (switch / rowsum), then scatter-add pointer probs
// (global atomics; same block wrote the row, stores drained at the barrier).
// Single read pass, no LDS staging.
// ---------------------------------------------------------------------------
__global__ __launch_bounds__(512) void k_final(
    const float* __restrict__ eL, const float* __restrict__ prob,
    const float* __restrict__ swp, const float* __restrict__ rowsum,
    const int* __restrict__ story, float* __restrict__ out, const int step)
{
    const int n = blockIdx.x;
    const int b = n & (Bq - 1);
    const int tid = threadIdx.x;
    const float swv = swp[n];
    const float scale = swv / rowsum[n];
    const float4* e4 = (const float4*)(eL + (size_t)n * Vq);
    float* orow = out + ((size_t)n * Lq + step) * Vq;
    float4* o4 = (float4*)orow;
    for (int v = tid; v < Vq / 4; v += 512) {
        const float4 e = e4[v];
        float4 o;
        o.x = e.x * scale; o.y = e.y * scale;
        o.z = e.z * scale; o.w = e.w * scale;
        o4[v] = o;
    }
    __syncthreads();
    __threadfence();
    if (tid < Tq) {
        const int idx = story[b * Tq + tid];
        atomicAdd(orow + idx, (1.f - swv) * prob[n * Tq + tid]);
    }
}

// ---------------------------------------------------------------------------
extern "C" void kernel_launch(void* const* d_in, const int* in_sizes, int n_in,
                              void* d_out, int out_size, void* d_ws, size_t ws_size,
                              hipStream_t stream)
{
    const float* ehid    = (const float*)d_in[0];
    const float* enc     = (const float*)d_in[1];
    const float* emb     = (const float*)d_in[2];
    const float* w_ih    = (const float*)d_in[3];
    const float* w_hh    = (const float*)d_in[4];
    const float* b_ih    = (const float*)d_in[5];
    const float* b_hh    = (const float*)d_in[6];
    const float* w_ratio = (const float*)d_in[7];
    const float* b_ratio = (const float*)d_in[8];
    const float* w_gate  = (const float*)d_in[9];
    const float* b_gate  = (const float*)d_in[10];
    const float* slot_emb= (const float*)d_in[11];
    const int*  lens     = (const int*)d_in[12];
    const int*  story    = (const int*)d_in[13];
    const int*  tgt      = (const int*)d_in[14];
    const int*  dom      = (const int*)d_in[15];
    const int*  slo      = (const int*)d_in[16];

    float* out = (float*)d_out;
    float* out_gates = out + (size_t)NSq * Bq * Lq * Vq;

    char* w = (char*)d_ws;
    size_t off = 0;
    auto alloc = [&](size_t bytes) -> void* {
        void* p = (void*)(w + off);
        off += (bytes + 255) & ~(size_t)255;
        return p;
    };
    bf16*  xbp    = (bf16*)alloc((size_t)Lq * Nq * Hq * 2);
    bf16*  xlin   = (bf16*)alloc((size_t)Lq * Nq * Hq * 2);
    bf16*  hbp    = (bf16*)alloc((size_t)Nq * Hq * 2);
    float* h      = (float*)alloc((size_t)Nq * Hq * 4);
    float* gi_all = (float*)alloc((size_t)Lq * Nq * H3q * 4);
    float* gh     = (float*)alloc((size_t)Nq * H3q * 4);
    float* prob   = (float*)alloc((size_t)Nq * Tq * 4);
    float* swp    = (float*)alloc((size_t)Nq * 4);
    float* rowsum = (float*)alloc((size_t)Nq * 4);
    float* eL     = (float*)alloc((size_t)Nq * Vq * 4);
    bf16*  embp   = (bf16*)alloc((size_t)NGV * NKT * 64 * 8 * 2);
    bf16*  wihp   = (bf16*)alloc((size_t)NGW * NKT * 64 * 8 * 2);
    bf16*  whhp   = (bf16*)alloc((size_t)NGW * NKT * 64 * 8 * 2);
    bf16*  encb   = (bf16*)alloc((size_t)Bq * Tq * Hq * 2);

    // ---- one-time prolog ----
    {
        int nf;
        nf = NGV * NKT * 64;  // 902400
        k_packf<<<dim3((nf + 255) / 256), dim3(256), 0, stream>>>(emb, embp, NGV, Vq);
        nf = NGW * NKT * 64;  // 60800
        k_packf<<<dim3((nf + 255) / 256), dim3(256), 0, stream>>>(w_ih, wihp, NGW, H3q);
        k_packf<<<dim3((nf + 255) / 256), dim3(256), 0, stream>>>(w_hh, whhp, NGW, H3q);
        const int n4 = (Bq * Tq * Hq) / 4;
        k_f2b4<<<dim3((n4 + 255) / 256), dim3(256), 0, stream>>>(enc, encb, n4);
        nf = Lq * NGH * NKT * 64;  // 240000
        k_xball<<<dim3((nf + 255) / 256), dim3(256), 0, stream>>>(
            slot_emb, dom, slo, emb, tgt, xbp, xlin);
        nf = NGH * NKT * 64;  // 24000
        k_h0<<<dim3((nf + 255) / 256), dim3(256), 0, stream>>>(ehid, h, hbp);
        k_gi_all<<<dim3(NGW, Lq), dim3(256), 0, stream>>>(xbp, wihp, gi_all);
    }

    // ---- decode loop: 4 kernels/step ----
    for (int step = 0; step < Lq; ++step) {
        k_gh<<<dim3(NGW, 4), dim3(256), 0, stream>>>(hbp, whhp, gh, rowsum);
        k_attn<<<dim3(Nq), dim3(256), 0, stream>>>(
            gi_all, gh, b_ih, b_hh, h, hbp, xlin, encb, lens, w_ratio, b_ratio,
            w_gate, b_gate, prob, swp, out_gates, step);
        k_vocab<<<dim3(282), dim3(256), 0, stream>>>(hbp, embp, eL, rowsum);
        k_final<<<dim3(Nq), dim3(512), 0, stream>>>(
            eL, prob, swp, rowsum, story, out, step);
    }
}

// Round 2
// 1553.779 us; speedup vs baseline: 2.1109x; 2.1109x over previous
//
#include <hip/hip_runtime.h>
#include <hip/hip_bf16.h>

#define Bq 16
#define Tq 256
#define Vq 18000
#define NSq 30
#define Lq 10
#define Gq 3
#define Hq 400
#define Nq (NSq * Bq)      // 480
#define H3q (3 * Hq)       // 1200
#define NKT 25             // 400 / 16 K-tiles
#define NGV 564            // embp col groups (564*32 = 18048 padded cols)
#define NGW 38             // weight col groups (1216 padded cols)
#define NGH 15             // h row groups (480 rows)
#define CHq 9000           // softmax LDS chunk (2 chunks cover V)
#define NPB 288            // padded partial stride (282 used)
#define NPB_USED 282       // vocab col-tile blocks

typedef __bf16 bf16;
typedef __bf16 bf16x4 __attribute__((ext_vector_type(4)));
typedef __bf16 bf16x8 __attribute__((ext_vector_type(8)));
typedef float floatx16 __attribute__((ext_vector_type(16)));

// ---------------------------------------------------------------------------
// K-1: f32 -> bf16 conversion (vectorized by 4). Used for enc only.
// ---------------------------------------------------------------------------
__global__ __launch_bounds__(256) void k_f2b4(
    const float* __restrict__ src, bf16* __restrict__ dst, const int n4)
{
    int i = blockIdx.x * 256 + threadIdx.x;
    if (i >= n4) return;
    const float4 v = ((const float4*)src)[i];
    bf16x4 o;
    o[0] = (bf16)v.x; o[1] = (bf16)v.y; o[2] = (bf16)v.z; o[3] = (bf16)v.w;
    ((bf16x4*)dst)[i] = o;
}

// ---------------------------------------------------------------------------
// Pack a row-major f32 [nrows][400] matrix into MFMA fragment-major bf16:
// frag f = ((g*25 + kt)*64 + lane), elem j:
//   src(row = g*32 + (lane&31), k = kt*16 + (lane>>5)*8 + j)
// so GEMM loads become lane-contiguous 16 B (fully coalesced).
// ---------------------------------------------------------------------------
__global__ __launch_bounds__(256) void k_packf(
    const float* __restrict__ src, bf16* __restrict__ dst,
    const int ngroups, const int nrows)
{
    const int i = blockIdx.x * 256 + threadIdx.x;
    if (i >= ngroups * NKT * 64) return;
    const int lane = i & 63;
    const int kt = (i >> 6) % NKT;
    const int g = i / (NKT * 64);
    int row = g * 32 + (lane & 31);
    if (row >= nrows) row = nrows - 1;
    const int k0 = kt * 16 + (lane >> 5) * 8;
    const float* s = src + (size_t)row * Hq + k0;
    const float4 a = *(const float4*)s;
    const float4 c = *(const float4*)(s + 4);
    bf16x8 o;
    o[0] = (bf16)a.x; o[1] = (bf16)a.y; o[2] = (bf16)a.z; o[3] = (bf16)a.w;
    o[4] = (bf16)c.x; o[5] = (bf16)c.y; o[6] = (bf16)c.z; o[7] = (bf16)c.w;
    *(bf16x8*)(dst + (size_t)i * 8) = o;
}

// ---------------------------------------------------------------------------
// Build ALL decoder inputs upfront (teacher forcing: targets known).
// ---------------------------------------------------------------------------
__global__ __launch_bounds__(256) void k_xball(
    const float* __restrict__ slot_emb, const int* __restrict__ dom,
    const int* __restrict__ slo, const float* __restrict__ emb,
    const int* __restrict__ tgt, bf16* __restrict__ xbp,
    bf16* __restrict__ xlin)
{
    const int i = blockIdx.x * 256 + threadIdx.x;
    if (i >= Lq * NGH * NKT * 64) return;
    const int lane = i & 63;
    const int kt = (i >> 6) % NKT;
    const int gg = i / (NKT * 64);
    const int g = gg % NGH;
    const int s = gg / NGH;
    const int n = g * 32 + (lane & 31);
    const int slot = n >> 4, b = n & (Bq - 1);
    const int k0 = kt * 16 + (lane >> 5) * 8;
    float v[8];
    if (s == 0) {
        const float* p1 = slot_emb + (size_t)dom[slot] * Hq + k0;
        const float* p2 = slot_emb + (size_t)slo[slot] * Hq + k0;
        #pragma unroll
        for (int j = 0; j < 8; ++j) v[j] = p1[j] + p2[j];
    } else {
        const int tv = tgt[(b * NSq + slot) * Lq + (s - 1)];
        const float* p = emb + (size_t)tv * Hq + k0;
        #pragma unroll
        for (int j = 0; j < 8; ++j) v[j] = p[j];
    }
    bf16x8 o;
    #pragma unroll
    for (int j = 0; j < 8; ++j) o[j] = (bf16)v[j];
    *(bf16x8*)(xbp + (size_t)i * 8) = o;
    *(bf16x8*)(xlin + ((size_t)(s * Nq + n)) * Hq + k0) = o;
}

// ---------------------------------------------------------------------------
// Init h (f32 state) and packed hbp from encoded_hidden.
// ---------------------------------------------------------------------------
__global__ __launch_bounds__(256) void k_h0(
    const float* __restrict__ ehid, float* __restrict__ h,
    bf16* __restrict__ hbp)
{
    const int i = blockIdx.x * 256 + threadIdx.x;
    if (i >= NGH * NKT * 64) return;
    const int lane = i & 63;
    const int kt = (i >> 6) % NKT;
    const int g = i / (NKT * 64);
    const int n = g * 32 + (lane & 31);
    const int b = n & (Bq - 1);
    const int k0 = kt * 16 + (lane >> 5) * 8;
    const float* s = ehid + (size_t)b * Hq + k0;
    bf16x8 o;
    #pragma unroll
    for (int j = 0; j < 8; ++j) {
        float v = s[j];
        h[(size_t)n * Hq + k0 + j] = v;
        o[j] = (bf16)v;
    }
    *(bf16x8*)(hbp + (size_t)i * 8) = o;
}

// ---------------------------------------------------------------------------
// gi for ALL 10 steps in one MFMA GEMM: (10*480) x 1200 x 400.
// ---------------------------------------------------------------------------
__global__ __launch_bounds__(256) void k_gi_all(
    const bf16* __restrict__ xbp, const bf16* __restrict__ wihp,
    float* __restrict__ gi_all)
{
    const int ct = blockIdx.x;
    const int s = blockIdx.y;
    const int wave = threadIdx.x >> 6, lane = threadIdx.x & 63;
    floatx16 acc[4];
    #pragma unroll
    for (int i = 0; i < 4; ++i)
        #pragma unroll
        for (int r = 0; r < 16; ++r) acc[i][r] = 0.f;
    for (int kt = 0; kt < NKT; ++kt) {
        const bf16x8 w = *(const bf16x8*)(wihp + ((size_t)(ct * NKT + kt) * 64 + lane) * 8);
        #pragma unroll
        for (int i = 0; i < 4; ++i) {
            const int g = wave + 4 * i;
            if (g < NGH) {
                const bf16x8 a = *(const bf16x8*)(xbp +
                    ((size_t)((s * NGH + g) * NKT + kt) * 64 + lane) * 8);
                acc[i] = __builtin_amdgcn_mfma_f32_32x32x16_bf16(a, w, acc[i], 0, 0, 0);
            }
        }
    }
    const int j = ct * 32 + (lane & 31);
    if (j >= H3q) return;
    #pragma unroll
    for (int i = 0; i < 4; ++i) {
        const int g = wave + 4 * i;
        if (g < NGH) {
            const int rbase = g * 32 + 4 * (lane >> 5);
            #pragma unroll
            for (int r = 0; r < 16; ++r) {
                const int rr = rbase + (r & 3) + 8 * (r >> 2);
                gi_all[((size_t)(s * Nq + rr)) * H3q + j] = acc[i][r];
            }
        }
    }
}

// ---------------------------------------------------------------------------
// Per-step: gh = h_prev @ W_hh^T (packed operands, coalesced).
// ---------------------------------------------------------------------------
__global__ __launch_bounds__(256) void k_gh(
    const bf16* __restrict__ hbp, const bf16* __restrict__ whhp,
    float* __restrict__ gh)
{
    const int ct = blockIdx.x;
    const int wave = threadIdx.x >> 6, lane = threadIdx.x & 63;
    const int g = blockIdx.y * 4 + wave;
    if (g >= NGH) return;
    floatx16 acc;
    #pragma unroll
    for (int r = 0; r < 16; ++r) acc[r] = 0.f;
    for (int kt = 0; kt < NKT; ++kt) {
        const bf16x8 a = *(const bf16x8*)(hbp + ((size_t)(g * NKT + kt) * 64 + lane) * 8);
        const bf16x8 w = *(const bf16x8*)(whhp + ((size_t)(ct * NKT + kt) * 64 + lane) * 8);
        acc = __builtin_amdgcn_mfma_f32_32x32x16_bf16(a, w, acc, 0, 0, 0);
    }
    const int j = ct * 32 + (lane & 31);
    if (j >= H3q) return;
    const int rbase = g * 32 + 4 * (lane >> 5);
    #pragma unroll
    for (int r = 0; r < 16; ++r) {
        const int rr = rbase + (r & 3) + 8 * (r >> 2);
        gh[(size_t)rr * H3q + j] = acc[r];
    }
}

// ---------------------------------------------------------------------------
// GRU nonlinearity + attention + context + switch (+gates at step 0).
// ---------------------------------------------------------------------------
__global__ __launch_bounds__(256) void k_attn(
    const float* __restrict__ gi_all, const float* __restrict__ gh,
    const float* __restrict__ b_ih, const float* __restrict__ b_hh,
    float* __restrict__ h, bf16* __restrict__ hbp,
    const bf16* __restrict__ xlin, const bf16* __restrict__ encb,
    const int* __restrict__ lens, const float* __restrict__ w_ratio,
    const float* __restrict__ b_ratio, const float* __restrict__ w_gate,
    const float* __restrict__ b_gate, float* __restrict__ prob,
    float* __restrict__ swp, float* __restrict__ out_gates, const int step)
{
    const int n = blockIdx.x;
    const int b = n & (Bq - 1);
    const int tid = threadIdx.x;
    __shared__ float s_h[Hq];
    __shared__ float s_c[Hq];
    __shared__ float s_p[Tq];
    __shared__ float s_red[4];

    const float* gin = gi_all + ((size_t)step * Nq + n) * H3q;
    const float* ghn = gh + (size_t)n * H3q;
    for (int k = tid; k < Hq; k += 256) {
        float ir = gin[k]          + b_ih[k];
        float hr = ghn[k]          + b_hh[k];
        float iz = gin[Hq + k]     + b_ih[Hq + k];
        float hz = ghn[Hq + k]     + b_hh[Hq + k];
        float in_ = gin[2*Hq + k]  + b_ih[2*Hq + k];
        float hn_ = ghn[2*Hq + k]  + b_hh[2*Hq + k];
        float r = 1.f / (1.f + __expf(-(ir + hr)));
        float z = 1.f / (1.f + __expf(-(iz + hz)));
        float nn = tanhf(in_ + r * hn_);
        float hp = h[(size_t)n * Hq + k];
        float hv = (1.f - z) * nn + z * hp;
        s_h[k] = hv;
        h[(size_t)n * Hq + k] = hv;
        hbp[((size_t)(((n >> 5) * NKT + (k >> 4)) * 64
                      + ((k >> 3) & 1) * 32 + (n & 31))) * 8 + (k & 7)] = (bf16)hv;
    }
    __syncthreads();

    // ---- scores: each wave handles 64 t's; 50 lanes x 8 cols, coalesced ----
    const int lane = tid & 63;
    const int wv = tid >> 6;
    float hreg[8];
    #pragma unroll
    for (int j = 0; j < 8; ++j) hreg[j] = 0.f;
    if (lane < 50) {
        #pragma unroll
        for (int j = 0; j < 8; ++j) hreg[j] = s_h[lane * 8 + j];
    }
    for (int it = 0; it < 64; ++it) {
        const int t = wv * 64 + it;
        float part = 0.f;
        if (lane < 50) {
            const bf16x8 e = *(const bf16x8*)(encb + ((size_t)(b * Tq + t)) * Hq + lane * 8);
            #pragma unroll
            for (int j = 0; j < 8; ++j) part += hreg[j] * (float)e[j];
        }
        #pragma unroll
        for (int off = 32; off > 0; off >>= 1) part += __shfl_xor(part, off, 64);
        if (lane == 0) s_p[t] = part;
    }
    __syncthreads();

    const int len = lens[b];
    float score = (tid < len) ? s_p[tid] : -1e9f;
    float mx = score;
    for (int off = 32; off > 0; off >>= 1) mx = fmaxf(mx, __shfl_xor(mx, off, 64));
    if ((tid & 63) == 0) s_red[tid >> 6] = mx;
    __syncthreads();
    mx = fmaxf(fmaxf(s_red[0], s_red[1]), fmaxf(s_red[2], s_red[3]));
    float ev = __expf(score - mx);
    float sm = ev;
    for (int off = 32; off > 0; off >>= 1) sm += __shfl_xor(sm, off, 64);
    __syncthreads();
    if ((tid & 63) == 0) s_red[tid >> 6] = sm;
    __syncthreads();
    sm = s_red[0] + s_red[1] + s_red[2] + s_red[3];
    float p = ev / sm;
    s_p[tid] = p;
    prob[n * Tq + tid] = p;
    __syncthreads();

    // context[k] = sum_t p[t] * enc[b][t][k]
    for (int k = tid; k < Hq; k += 256) {
        float c = 0.f;
        const bf16* ecol = encb + (size_t)b * Tq * Hq + k;
        for (int tt = 0; tt < Tq; ++tt) c += s_p[tt] * (float)ecol[(size_t)tt * Hq];
        s_c[k] = c;
    }
    __syncthreads();

    const bf16* xr = xlin + ((size_t)step * Nq + n) * Hq;
    float part2 = 0.f;
    for (int k = tid; k < Hq; k += 256) {
        part2 += w_ratio[k]        * s_h[k]
               + w_ratio[Hq + k]   * s_c[k]
               + w_ratio[2*Hq + k] * (float)xr[k];
    }
    for (int off = 32; off > 0; off >>= 1) part2 += __shfl_xor(part2, off, 64);
    __syncthreads();
    if ((tid & 63) == 0) s_red[tid >> 6] = part2;
    __syncthreads();
    if (tid == 0) {
        float tot = s_red[0] + s_red[1] + s_red[2] + s_red[3] + b_ratio[0];
        swp[n] = 1.f / (1.f + __expf(-tot));
    }

    if (step == 0) {
        for (int gg = 0; gg < Gq; ++gg) {
            float pg = 0.f;
            for (int k = tid; k < Hq; k += 256)
                pg += w_gate[gg * Hq + k] * s_c[k];
            for (int off = 32; off > 0; off >>= 1) pg += __shfl_xor(pg, off, 64);
            __syncthreads();
            if ((tid & 63) == 0) s_red[tid >> 6] = pg;
            __syncthreads();
            if (tid == 0)
                out_gates[n * Gq + gg] =
                    s_red[0] + s_red[1] + s_red[2] + s_red[3] + b_gate[gg];
        }
    }
}

// ---------------------------------------------------------------------------
// Vocab GEMM (480 x 18000 x 400), packed operands, 64 cols/block.
// Epilogue: e = exp(logit) stored to eL (max-free softmax; |logit| <~ 15).
// Per-block row-sum contributions -> partial[rr][ct2] (plain stores, each
// cell written exactly once -- NO global atomics).
// ---------------------------------------------------------------------------
__global__ __launch_bounds__(256, 2) void k_vocab(
    const bf16* __restrict__ hbp, const bf16* __restrict__ embp,
    float* __restrict__ eL, float* __restrict__ partial)
{
    const int ct2 = blockIdx.x;           // 0..281 (64 cols each)
    const int wave = threadIdx.x >> 6, lane = threadIdx.x & 63;
    floatx16 acc0[4], acc1[4];
    #pragma unroll
    for (int i = 0; i < 4; ++i)
        #pragma unroll
        for (int r = 0; r < 16; ++r) { acc0[i][r] = 0.f; acc1[i][r] = 0.f; }

    for (int kt = 0; kt < NKT; ++kt) {
        const bf16x8 w0 = *(const bf16x8*)(embp +
            ((size_t)((2 * ct2) * NKT + kt) * 64 + lane) * 8);
        const bf16x8 w1 = *(const bf16x8*)(embp +
            ((size_t)((2 * ct2 + 1) * NKT + kt) * 64 + lane) * 8);
        #pragma unroll
        for (int i = 0; i < 4; ++i) {
            const int g = wave + 4 * i;
            if (g < NGH) {
                const bf16x8 a = *(const bf16x8*)(hbp +
                    ((size_t)(g * NKT + kt) * 64 + lane) * 8);
                acc0[i] = __builtin_amdgcn_mfma_f32_32x32x16_bf16(a, w0, acc0[i], 0, 0, 0);
                acc1[i] = __builtin_amdgcn_mfma_f32_32x32x16_bf16(a, w1, acc1[i], 0, 0, 0);
            }
        }
    }

    const int mcol = lane & 31, half = lane >> 5;
    const int j0 = ct2 * 64 + mcol, j1 = j0 + 32;
    #pragma unroll
    for (int i = 0; i < 4; ++i) {
        const int g = wave + 4 * i;       // wave-uniform -> shfl below is safe
        if (g >= NGH) continue;
        const int rbase = g * 32 + 4 * half;
        #pragma unroll
        for (int r = 0; r < 16; ++r) {
            const int rr = rbase + (r & 3) + 8 * (r >> 2);
            const float e0 = (j0 < Vq) ? __expf(acc0[i][r]) : 0.f;
            const float e1 = (j1 < Vq) ? __expf(acc1[i][r]) : 0.f;
            if (j0 < Vq) eL[(size_t)rr * Vq + j0] = e0;
            if (j1 < Vq) eL[(size_t)rr * Vq + j1] = e1;
            float v = e0 + e1;
            v += __shfl_xor(v, 16, 64);
            v += __shfl_xor(v, 8, 64);
            v += __shfl_xor(v, 4, 64);
            v += __shfl_xor(v, 2, 64);
            v += __shfl_xor(v, 1, 64);
            if (mcol == 0) partial[(size_t)rr * NPB + ct2] = v;
        }
    }
}

// ---------------------------------------------------------------------------
// Final: reduce per-row partials -> rowsum; then 2x36KB LDS chunks:
// load eL once, scale, LDS-atomic scatter of pointer probs, coalesced store.
// No global atomics.
// ---------------------------------------------------------------------------
__global__ __launch_bounds__(512) void k_final(
    const float* __restrict__ eL, const float* __restrict__ prob,
    const float* __restrict__ swp, const float* __restrict__ partial,
    const int* __restrict__ story, float* __restrict__ out, const int step)
{
    __shared__ __align__(16) float s_chunk[CHq];
    __shared__ float s_red[8];
    const int n = blockIdx.x;
    const int b = n & (Bq - 1);
    const int tid = threadIdx.x;

    float ps = 0.f;
    if (tid < NPB_USED) ps = partial[(size_t)n * NPB + tid];
    #pragma unroll
    for (int off = 32; off > 0; off >>= 1) ps += __shfl_xor(ps, off, 64);
    if ((tid & 63) == 0) s_red[tid >> 6] = ps;
    __syncthreads();
    float rs = 0.f;
    #pragma unroll
    for (int i = 0; i < 8; ++i) rs += s_red[i];
    const float swv = swp[n];
    const float scale = swv / rs;
    const float4* e4 = (const float4*)(eL + (size_t)n * Vq);
    float* orow = out + ((size_t)n * Lq + step) * Vq;

    #pragma unroll
    for (int c = 0; c < 2; ++c) {
        const int c0 = c * CHq;
        float4* s4 = (float4*)s_chunk;
        for (int v = tid; v < CHq / 4; v += 512) {
            float4 e = e4[c * (CHq / 4) + v];
            e.x *= scale; e.y *= scale; e.z *= scale; e.w *= scale;
            s4[v] = e;
        }
        __syncthreads();
        if (tid < Tq) {
            const int idx = story[b * Tq + tid];
            if (idx >= c0 && idx < c0 + CHq)
                atomicAdd(&s_chunk[idx - c0], (1.f - swv) * prob[n * Tq + tid]);
        }
        __syncthreads();
        float4* o4 = (float4*)(orow + c0);
        for (int v = tid; v < CHq / 4; v += 512)
            o4[v] = s4[v];
        if (c == 0) __syncthreads();
    }
}

// ---------------------------------------------------------------------------
extern "C" void kernel_launch(void* const* d_in, const int* in_sizes, int n_in,
                              void* d_out, int out_size, void* d_ws, size_t ws_size,
                              hipStream_t stream)
{
    const float* ehid    = (const float*)d_in[0];
    const float* enc     = (const float*)d_in[1];
    const float* emb     = (const float*)d_in[2];
    const float* w_ih    = (const float*)d_in[3];
    const float* w_hh    = (const float*)d_in[4];
    const float* b_ih    = (const float*)d_in[5];
    const float* b_hh    = (const float*)d_in[6];
    const float* w_ratio = (const float*)d_in[7];
    const float* b_ratio = (const float*)d_in[8];
    const float* w_gate  = (const float*)d_in[9];
    const float* b_gate  = (const float*)d_in[10];
    const float* slot_emb= (const float*)d_in[11];
    const int*  lens     = (const int*)d_in[12];
    const int*  story    = (const int*)d_in[13];
    const int*  tgt      = (const int*)d_in[14];
    const int*  dom      = (const int*)d_in[15];
    const int*  slo      = (const int*)d_in[16];

    float* out = (float*)d_out;
    float* out_gates = out + (size_t)NSq * Bq * Lq * Vq;

    char* w = (char*)d_ws;
    size_t off = 0;
    auto alloc = [&](size_t bytes) -> void* {
        void* p = (void*)(w + off);
        off += (bytes + 255) & ~(size_t)255;
        return p;
    };
    bf16*  xbp    = (bf16*)alloc((size_t)Lq * Nq * Hq * 2);
    bf16*  xlin   = (bf16*)alloc((size_t)Lq * Nq * Hq * 2);
    bf16*  hbp    = (bf16*)alloc((size_t)Nq * Hq * 2);
    float* h      = (float*)alloc((size_t)Nq * Hq * 4);
    float* gi_all = (float*)alloc((size_t)Lq * Nq * H3q * 4);
    float* gh     = (float*)alloc((size_t)Nq * H3q * 4);
    float* prob   = (float*)alloc((size_t)Nq * Tq * 4);
    float* swp    = (float*)alloc((size_t)Nq * 4);
    float* partial= (float*)alloc((size_t)Nq * NPB * 4);
    float* eL     = (float*)alloc((size_t)Nq * Vq * 4);
    bf16*  embp   = (bf16*)alloc((size_t)NGV * NKT * 64 * 8 * 2);
    bf16*  wihp   = (bf16*)alloc((size_t)NGW * NKT * 64 * 8 * 2);
    bf16*  whhp   = (bf16*)alloc((size_t)NGW * NKT * 64 * 8 * 2);
    bf16*  encb   = (bf16*)alloc((size_t)Bq * Tq * Hq * 2);

    // ---- one-time prolog ----
    {
        int nf;
        nf = NGV * NKT * 64;  // 902400
        k_packf<<<dim3((nf + 255) / 256), dim3(256), 0, stream>>>(emb, embp, NGV, Vq);
        nf = NGW * NKT * 64;  // 60800
        k_packf<<<dim3((nf + 255) / 256), dim3(256), 0, stream>>>(w_ih, wihp, NGW, H3q);
        k_packf<<<dim3((nf + 255) / 256), dim3(256), 0, stream>>>(w_hh, whhp, NGW, H3q);
        const int n4 = (Bq * Tq * Hq) / 4;
        k_f2b4<<<dim3((n4 + 255) / 256), dim3(256), 0, stream>>>(enc, encb, n4);
        nf = Lq * NGH * NKT * 64;  // 240000
        k_xball<<<dim3((nf + 255) / 256), dim3(256), 0, stream>>>(
            slot_emb, dom, slo, emb, tgt, xbp, xlin);
        nf = NGH * NKT * 64;  // 24000
        k_h0<<<dim3((nf + 255) / 256), dim3(256), 0, stream>>>(ehid, h, hbp);
        k_gi_all<<<dim3(NGW, Lq), dim3(256), 0, stream>>>(xbp, wihp, gi_all);
    }

    // ---- decode loop: 4 kernels/step ----
    for (int step = 0; step < Lq; ++step) {
        k_gh<<<dim3(NGW, 4), dim3(256), 0, stream>>>(hbp, whhp, gh);
        k_attn<<<dim3(Nq), dim3(256), 0, stream>>>(
            gi_all, gh, b_ih, b_hh, h, hbp, xlin, encb, lens, w_ratio, b_ratio,
            w_gate, b_gate, prob, swp, out_gates, step);
        k_vocab<<<dim3(NPB_USED), dim3(256), 0, stream>>>(hbp, embp, eL, partial);
        k_final<<<dim3(Nq), dim3(512), 0, stream>>>(
            eL, prob, swp, partial, story, out, step);
    }
}

// Round 3
// 1203.111 us; speedup vs baseline: 2.7261x; 1.2915x over previous
//
#include <hip/hip_runtime.h>
#include <hip/hip_bf16.h>

#define Bq 16
#define Tq 256
#define Vq 18000
#define NSq 30
#define Lq 10
#define Gq 3
#define Hq 400
#define Nq (NSq * Bq)      // 480
#define H3q (3 * Hq)       // 1200
#define NKT 25             // 400 / 16 K-tiles
#define NGV 564            // embp col groups (564*32 = 18048 padded cols)
#define NGW 38             // weight col groups (1216 padded cols)
#define NGH 15             // h row groups (480 rows)
#define CHq 9000           // softmax LDS chunk (2 chunks cover V)
#define NPB 288            // padded partial stride (282 used)
#define NPB_USED 282       // vocab col-tile blocks
#define NGHB 152           // gh blocks fused after vocab (38 ct x 4 gsets)

typedef __bf16 bf16;
typedef __bf16 bf16x4 __attribute__((ext_vector_type(4)));
typedef __bf16 bf16x8 __attribute__((ext_vector_type(8)));
typedef float floatx16 __attribute__((ext_vector_type(16)));

// ---------------------------------------------------------------------------
// f32 -> bf16 conversion (vectorized by 4). Used for enc only.
// ---------------------------------------------------------------------------
__global__ __launch_bounds__(256) void k_f2b4(
    const float* __restrict__ src, bf16* __restrict__ dst, const int n4)
{
    int i = blockIdx.x * 256 + threadIdx.x;
    if (i >= n4) return;
    const float4 v = ((const float4*)src)[i];
    bf16x4 o;
    o[0] = (bf16)v.x; o[1] = (bf16)v.y; o[2] = (bf16)v.z; o[3] = (bf16)v.w;
    ((bf16x4*)dst)[i] = o;
}

// ---------------------------------------------------------------------------
// Pack a row-major f32 [nrows][400] matrix into MFMA fragment-major bf16:
// frag f = ((g*25 + kt)*64 + lane), elem j:
//   src(row = g*32 + (lane&31), k = kt*16 + (lane>>5)*8 + j)
// ---------------------------------------------------------------------------
__global__ __launch_bounds__(256) void k_packf(
    const float* __restrict__ src, bf16* __restrict__ dst,
    const int ngroups, const int nrows)
{
    const int i = blockIdx.x * 256 + threadIdx.x;
    if (i >= ngroups * NKT * 64) return;
    const int lane = i & 63;
    const int kt = (i >> 6) % NKT;
    const int g = i / (NKT * 64);
    int row = g * 32 + (lane & 31);
    if (row >= nrows) row = nrows - 1;
    const int k0 = kt * 16 + (lane >> 5) * 8;
    const float* s = src + (size_t)row * Hq + k0;
    const float4 a = *(const float4*)s;
    const float4 c = *(const float4*)(s + 4);
    bf16x8 o;
    o[0] = (bf16)a.x; o[1] = (bf16)a.y; o[2] = (bf16)a.z; o[3] = (bf16)a.w;
    o[4] = (bf16)c.x; o[5] = (bf16)c.y; o[6] = (bf16)c.z; o[7] = (bf16)c.w;
    *(bf16x8*)(dst + (size_t)i * 8) = o;
}

// ---------------------------------------------------------------------------
// Build ALL decoder inputs upfront (teacher forcing: targets known).
// ---------------------------------------------------------------------------
__global__ __launch_bounds__(256) void k_xball(
    const float* __restrict__ slot_emb, const int* __restrict__ dom,
    const int* __restrict__ slo, const float* __restrict__ emb,
    const int* __restrict__ tgt, bf16* __restrict__ xbp,
    bf16* __restrict__ xlin)
{
    const int i = blockIdx.x * 256 + threadIdx.x;
    if (i >= Lq * NGH * NKT * 64) return;
    const int lane = i & 63;
    const int kt = (i >> 6) % NKT;
    const int gg = i / (NKT * 64);
    const int g = gg % NGH;
    const int s = gg / NGH;
    const int n = g * 32 + (lane & 31);
    const int slot = n >> 4, b = n & (Bq - 1);
    const int k0 = kt * 16 + (lane >> 5) * 8;
    float v[8];
    if (s == 0) {
        const float* p1 = slot_emb + (size_t)dom[slot] * Hq + k0;
        const float* p2 = slot_emb + (size_t)slo[slot] * Hq + k0;
        #pragma unroll
        for (int j = 0; j < 8; ++j) v[j] = p1[j] + p2[j];
    } else {
        const int tv = tgt[(b * NSq + slot) * Lq + (s - 1)];
        const float* p = emb + (size_t)tv * Hq + k0;
        #pragma unroll
        for (int j = 0; j < 8; ++j) v[j] = p[j];
    }
    bf16x8 o;
    #pragma unroll
    for (int j = 0; j < 8; ++j) o[j] = (bf16)v[j];
    *(bf16x8*)(xbp + (size_t)i * 8) = o;
    *(bf16x8*)(xlin + ((size_t)(s * Nq + n)) * Hq + k0) = o;
}

// ---------------------------------------------------------------------------
// Init h (f32 state) and packed hbp from encoded_hidden.
// ---------------------------------------------------------------------------
__global__ __launch_bounds__(256) void k_h0(
    const float* __restrict__ ehid, float* __restrict__ h,
    bf16* __restrict__ hbp)
{
    const int i = blockIdx.x * 256 + threadIdx.x;
    if (i >= NGH * NKT * 64) return;
    const int lane = i & 63;
    const int kt = (i >> 6) % NKT;
    const int g = i / (NKT * 64);
    const int n = g * 32 + (lane & 31);
    const int b = n & (Bq - 1);
    const int k0 = kt * 16 + (lane >> 5) * 8;
    const float* s = ehid + (size_t)b * Hq + k0;
    bf16x8 o;
    #pragma unroll
    for (int j = 0; j < 8; ++j) {
        float v = s[j];
        h[(size_t)n * Hq + k0 + j] = v;
        o[j] = (bf16)v;
    }
    *(bf16x8*)(hbp + (size_t)i * 8) = o;
}

// ---------------------------------------------------------------------------
// gi for ALL 10 steps in one MFMA GEMM: (10*480) x 1200 x 400.
// ---------------------------------------------------------------------------
__global__ __launch_bounds__(256) void k_gi_all(
    const bf16* __restrict__ xbp, const bf16* __restrict__ wihp,
    float* __restrict__ gi_all)
{
    const int ct = blockIdx.x;
    const int s = blockIdx.y;
    const int wave = threadIdx.x >> 6, lane = threadIdx.x & 63;
    floatx16 acc[4];
    #pragma unroll
    for (int i = 0; i < 4; ++i)
        #pragma unroll
        for (int r = 0; r < 16; ++r) acc[i][r] = 0.f;
    for (int kt = 0; kt < NKT; ++kt) {
        const bf16x8 w = *(const bf16x8*)(wihp + ((size_t)(ct * NKT + kt) * 64 + lane) * 8);
        #pragma unroll
        for (int i = 0; i < 4; ++i) {
            const int g = wave + 4 * i;
            if (g < NGH) {
                const bf16x8 a = *(const bf16x8*)(xbp +
                    ((size_t)((s * NGH + g) * NKT + kt) * 64 + lane) * 8);
                acc[i] = __builtin_amdgcn_mfma_f32_32x32x16_bf16(a, w, acc[i], 0, 0, 0);
            }
        }
    }
    const int j = ct * 32 + (lane & 31);
    if (j >= H3q) return;
    #pragma unroll
    for (int i = 0; i < 4; ++i) {
        const int g = wave + 4 * i;
        if (g < NGH) {
            const int rbase = g * 32 + 4 * (lane >> 5);
            #pragma unroll
            for (int r = 0; r < 16; ++r) {
                const int rr = rbase + (r & 3) + 8 * (r >> 2);
                gi_all[((size_t)(s * Nq + rr)) * H3q + j] = acc[i][r];
            }
        }
    }
}

// ---------------------------------------------------------------------------
// Standalone gh = h_prev @ W_hh^T (used once, for step 0).
// ---------------------------------------------------------------------------
__global__ __launch_bounds__(256) void k_gh(
    const bf16* __restrict__ hbp, const bf16* __restrict__ whhp,
    float* __restrict__ gh)
{
    const int ct = blockIdx.x;
    const int wave = threadIdx.x >> 6, lane = threadIdx.x & 63;
    const int g = blockIdx.y * 4 + wave;
    if (g >= NGH) return;
    floatx16 acc;
    #pragma unroll
    for (int r = 0; r < 16; ++r) acc[r] = 0.f;
    for (int kt = 0; kt < NKT; ++kt) {
        const bf16x8 a = *(const bf16x8*)(hbp + ((size_t)(g * NKT + kt) * 64 + lane) * 8);
        const bf16x8 w = *(const bf16x8*)(whhp + ((size_t)(ct * NKT + kt) * 64 + lane) * 8);
        acc = __builtin_amdgcn_mfma_f32_32x32x16_bf16(a, w, acc, 0, 0, 0);
    }
    const int j = ct * 32 + (lane & 31);
    if (j >= H3q) return;
    const int rbase = g * 32 + 4 * (lane >> 5);
    #pragma unroll
    for (int r = 0; r < 16; ++r) {
        const int rr = rbase + (r & 3) + 8 * (r >> 2);
        gh[(size_t)rr * H3q + j] = acc[r];
    }
}

// ---------------------------------------------------------------------------
// GRU nonlinearity + attention + context + switch (+gates at step 0).
// Scores phase: per-thread t (round-0 proven pattern; ILP-pipelined loads).
// ---------------------------------------------------------------------------
__global__ __launch_bounds__(256) void k_attn(
    const float* __restrict__ gi_all, const float* __restrict__ gh,
    const float* __restrict__ b_ih, const float* __restrict__ b_hh,
    float* __restrict__ h, bf16* __restrict__ hbp,
    const bf16* __restrict__ xlin, const bf16* __restrict__ encb,
    const int* __restrict__ lens, const float* __restrict__ w_ratio,
    const float* __restrict__ b_ratio, const float* __restrict__ w_gate,
    const float* __restrict__ b_gate, float* __restrict__ prob,
    float* __restrict__ swp, float* __restrict__ out_gates, const int step)
{
    const int n = blockIdx.x;
    const int b = n & (Bq - 1);
    const int tid = threadIdx.x;
    __shared__ float s_h[Hq];
    __shared__ float s_c[Hq];
    __shared__ float s_p[Tq];
    __shared__ float s_red[4];

    const float* gin = gi_all + ((size_t)step * Nq + n) * H3q;
    const float* ghn = gh + (size_t)n * H3q;
    for (int k = tid; k < Hq; k += 256) {
        float ir = gin[k]          + b_ih[k];
        float hr = ghn[k]          + b_hh[k];
        float iz = gin[Hq + k]     + b_ih[Hq + k];
        float hz = ghn[Hq + k]     + b_hh[Hq + k];
        float in_ = gin[2*Hq + k]  + b_ih[2*Hq + k];
        float hn_ = ghn[2*Hq + k]  + b_hh[2*Hq + k];
        float r = 1.f / (1.f + __expf(-(ir + hr)));
        float z = 1.f / (1.f + __expf(-(iz + hz)));
        float nn = tanhf(in_ + r * hn_);
        float hp = h[(size_t)n * Hq + k];
        float hv = (1.f - z) * nn + z * hp;
        s_h[k] = hv;
        h[(size_t)n * Hq + k] = hv;
        hbp[((size_t)(((n >> 5) * NKT + (k >> 4)) * 64
                      + ((k >> 3) & 1) * 32 + (n & 31))) * 8 + (k & 7)] = (bf16)hv;
    }
    __syncthreads();

    // ---- scores: thread t over T=256 (independent, ILP-friendly) ----
    const int t = tid;
    const bf16* erow = encb + (size_t)(b * Tq + t) * Hq;
    float sc = 0.f;
    #pragma unroll 5
    for (int kc = 0; kc < Hq / 8; ++kc) {
        bf16x8 e = *(const bf16x8*)(erow + kc * 8);
        #pragma unroll
        for (int j = 0; j < 8; ++j) sc += s_h[kc * 8 + j] * (float)e[j];
    }
    const int len = lens[b];
    float score = (t < len) ? sc : -1e9f;

    float mx = score;
    for (int off = 32; off > 0; off >>= 1) mx = fmaxf(mx, __shfl_xor(mx, off, 64));
    if ((tid & 63) == 0) s_red[tid >> 6] = mx;
    __syncthreads();
    mx = fmaxf(fmaxf(s_red[0], s_red[1]), fmaxf(s_red[2], s_red[3]));
    float ev = __expf(score - mx);
    float sm = ev;
    for (int off = 32; off > 0; off >>= 1) sm += __shfl_xor(sm, off, 64);
    __syncthreads();
    if ((tid & 63) == 0) s_red[tid >> 6] = sm;
    __syncthreads();
    sm = s_red[0] + s_red[1] + s_red[2] + s_red[3];
    float p = ev / sm;
    s_p[t] = p;
    prob[n * Tq + t] = p;
    __syncthreads();

    // context[k] = sum_t p[t] * enc[b][t][k]  (lanes coalesced in k)
    for (int k = tid; k < Hq; k += 256) {
        float c = 0.f;
        const bf16* ecol = encb + (size_t)b * Tq * Hq + k;
        for (int tt = 0; tt < Tq; ++tt) c += s_p[tt] * (float)ecol[(size_t)tt * Hq];
        s_c[k] = c;
    }
    __syncthreads();

    const bf16* xr = xlin + ((size_t)step * Nq + n) * Hq;
    float part2 = 0.f;
    for (int k = tid; k < Hq; k += 256) {
        part2 += w_ratio[k]        * s_h[k]
               + w_ratio[Hq + k]   * s_c[k]
               + w_ratio[2*Hq + k] * (float)xr[k];
    }
    for (int off = 32; off > 0; off >>= 1) part2 += __shfl_xor(part2, off, 64);
    __syncthreads();
    if ((tid & 63) == 0) s_red[tid >> 6] = part2;
    __syncthreads();
    if (tid == 0) {
        float tot = s_red[0] + s_red[1] + s_red[2] + s_red[3] + b_ratio[0];
        swp[n] = 1.f / (1.f + __expf(-tot));
    }

    if (step == 0) {
        for (int gg = 0; gg < Gq; ++gg) {
            float pg = 0.f;
            for (int k = tid; k < Hq; k += 256)
                pg += w_gate[gg * Hq + k] * s_c[k];
            for (int off = 32; off > 0; off >>= 1) pg += __shfl_xor(pg, off, 64);
            __syncthreads();
            if ((tid & 63) == 0) s_red[tid >> 6] = pg;
            __syncthreads();
            if (tid == 0)
                out_gates[n * Gq + gg] =
                    s_red[0] + s_red[1] + s_red[2] + s_red[3] + b_gate[gg];
        }
    }
}

// ---------------------------------------------------------------------------
// Fused: blocks <282 do the vocab GEMM epilogue (exp + per-block partial
// row sums, plain stores); blocks >=282 compute gh for the NEXT step
// (both consume the same hbp = h of the current step).
// ---------------------------------------------------------------------------
__global__ __launch_bounds__(256, 2) void k_vocab_gh(
    const bf16* __restrict__ hbp, const bf16* __restrict__ embp,
    const bf16* __restrict__ whhp, float* __restrict__ eL,
    float* __restrict__ partial, float* __restrict__ gh)
{
    const int wave = threadIdx.x >> 6, lane = threadIdx.x & 63;

    if (blockIdx.x >= NPB_USED) {
        // ---- gh GEMM for next step ----
        const int bid2 = blockIdx.x - NPB_USED;
        const int ct = bid2 % NGW;
        const int g = (bid2 / NGW) * 4 + wave;
        if (g >= NGH) return;
        floatx16 acc;
        #pragma unroll
        for (int r = 0; r < 16; ++r) acc[r] = 0.f;
        for (int kt = 0; kt < NKT; ++kt) {
            const bf16x8 a = *(const bf16x8*)(hbp + ((size_t)(g * NKT + kt) * 64 + lane) * 8);
            const bf16x8 w = *(const bf16x8*)(whhp + ((size_t)(ct * NKT + kt) * 64 + lane) * 8);
            acc = __builtin_amdgcn_mfma_f32_32x32x16_bf16(a, w, acc, 0, 0, 0);
        }
        const int j = ct * 32 + (lane & 31);
        if (j >= H3q) return;
        const int rbase = g * 32 + 4 * (lane >> 5);
        #pragma unroll
        for (int r = 0; r < 16; ++r) {
            const int rr = rbase + (r & 3) + 8 * (r >> 2);
            gh[(size_t)rr * H3q + j] = acc[r];
        }
        return;
    }

    // ---- vocab GEMM (64 cols per block) ----
    const int ct2 = blockIdx.x;
    floatx16 acc0[4], acc1[4];
    #pragma unroll
    for (int i = 0; i < 4; ++i)
        #pragma unroll
        for (int r = 0; r < 16; ++r) { acc0[i][r] = 0.f; acc1[i][r] = 0.f; }

    for (int kt = 0; kt < NKT; ++kt) {
        const bf16x8 w0 = *(const bf16x8*)(embp +
            ((size_t)((2 * ct2) * NKT + kt) * 64 + lane) * 8);
        const bf16x8 w1 = *(const bf16x8*)(embp +
            ((size_t)((2 * ct2 + 1) * NKT + kt) * 64 + lane) * 8);
        #pragma unroll
        for (int i = 0; i < 4; ++i) {
            const int g = wave + 4 * i;
            if (g < NGH) {
                const bf16x8 a = *(const bf16x8*)(hbp +
                    ((size_t)(g * NKT + kt) * 64 + lane) * 8);
                acc0[i] = __builtin_amdgcn_mfma_f32_32x32x16_bf16(a, w0, acc0[i], 0, 0, 0);
                acc1[i] = __builtin_amdgcn_mfma_f32_32x32x16_bf16(a, w1, acc1[i], 0, 0, 0);
            }
        }
    }

    const int mcol = lane & 31, half = lane >> 5;
    const int j0 = ct2 * 64 + mcol, j1 = j0 + 32;
    #pragma unroll
    for (int i = 0; i < 4; ++i) {
        const int g = wave + 4 * i;       // wave-uniform -> shfl below is safe
        if (g >= NGH) continue;
        const int rbase = g * 32 + 4 * half;
        #pragma unroll
        for (int r = 0; r < 16; ++r) {
            const int rr = rbase + (r & 3) + 8 * (r >> 2);
            const float e0 = (j0 < Vq) ? __expf(acc0[i][r]) : 0.f;
            const float e1 = (j1 < Vq) ? __expf(acc1[i][r]) : 0.f;
            if (j0 < Vq) eL[(size_t)rr * Vq + j0] = e0;
            if (j1 < Vq) eL[(size_t)rr * Vq + j1] = e1;
            float v = e0 + e1;
            v += __shfl_xor(v, 16, 64);
            v += __shfl_xor(v, 8, 64);
            v += __shfl_xor(v, 4, 64);
            v += __shfl_xor(v, 2, 64);
            v += __shfl_xor(v, 1, 64);
            if (mcol == 0) partial[(size_t)rr * NPB + ct2] = v;
        }
    }
}

// ---------------------------------------------------------------------------
// Final: reduce per-row partials -> rowsum; then 2x36KB LDS chunks:
// load eL once, scale, LDS-atomic scatter of pointer probs, coalesced store.
// ---------------------------------------------------------------------------
__global__ __launch_bounds__(512) void k_final(
    const float* __restrict__ eL, const float* __restrict__ prob,
    const float* __restrict__ swp, const float* __restrict__ partial,
    const int* __restrict__ story, float* __restrict__ out, const int step)
{
    __shared__ __align__(16) float s_chunk[CHq];
    __shared__ float s_red[8];
    const int n = blockIdx.x;
    const int b = n & (Bq - 1);
    const int tid = threadIdx.x;

    float ps = 0.f;
    if (tid < NPB_USED) ps = partial[(size_t)n * NPB + tid];
    #pragma unroll
    for (int off = 32; off > 0; off >>= 1) ps += __shfl_xor(ps, off, 64);
    if ((tid & 63) == 0) s_red[tid >> 6] = ps;
    __syncthreads();
    float rs = 0.f;
    #pragma unroll
    for (int i = 0; i < 8; ++i) rs += s_red[i];
    const float swv = swp[n];
    const float scale = swv / rs;
    const float4* e4 = (const float4*)(eL + (size_t)n * Vq);
    float* orow = out + ((size_t)n * Lq + step) * Vq;

    #pragma unroll
    for (int c = 0; c < 2; ++c) {
        const int c0 = c * CHq;
        float4* s4 = (float4*)s_chunk;
        for (int v = tid; v < CHq / 4; v += 512) {
            float4 e = e4[c * (CHq / 4) + v];
            e.x *= scale; e.y *= scale; e.z *= scale; e.w *= scale;
            s4[v] = e;
        }
        __syncthreads();
        if (tid < Tq) {
            const int idx = story[b * Tq + tid];
            if (idx >= c0 && idx < c0 + CHq)
                atomicAdd(&s_chunk[idx - c0], (1.f - swv) * prob[n * Tq + tid]);
        }
        __syncthreads();
        float4* o4 = (float4*)(orow + c0);
        for (int v = tid; v < CHq / 4; v += 512)
            o4[v] = s4[v];
        if (c == 0) __syncthreads();
    }
}

// ---------------------------------------------------------------------------
extern "C" void kernel_launch(void* const* d_in, const int* in_sizes, int n_in,
                              void* d_out, int out_size, void* d_ws, size_t ws_size,
                              hipStream_t stream)
{
    const float* ehid    = (const float*)d_in[0];
    const float* enc     = (const float*)d_in[1];
    const float* emb     = (const float*)d_in[2];
    const float* w_ih    = (const float*)d_in[3];
    const float* w_hh    = (const float*)d_in[4];
    const float* b_ih    = (const float*)d_in[5];
    const float* b_hh    = (const float*)d_in[6];
    const float* w_ratio = (const float*)d_in[7];
    const float* b_ratio = (const float*)d_in[8];
    const float* w_gate  = (const float*)d_in[9];
    const float* b_gate  = (const float*)d_in[10];
    const float* slot_emb= (const float*)d_in[11];
    const int*  lens     = (const int*)d_in[12];
    const int*  story    = (const int*)d_in[13];
    const int*  tgt      = (const int*)d_in[14];
    const int*  dom      = (const int*)d_in[15];
    const int*  slo      = (const int*)d_in[16];

    float* out = (float*)d_out;
    float* out_gates = out + (size_t)NSq * Bq * Lq * Vq;

    char* w = (char*)d_ws;
    size_t off = 0;
    auto alloc = [&](size_t bytes) -> void* {
        void* p = (void*)(w + off);
        off += (bytes + 255) & ~(size_t)255;
        return p;
    };
    bf16*  xbp    = (bf16*)alloc((size_t)Lq * Nq * Hq * 2);
    bf16*  xlin   = (bf16*)alloc((size_t)Lq * Nq * Hq * 2);
    bf16*  hbp    = (bf16*)alloc((size_t)Nq * Hq * 2);
    float* h      = (float*)alloc((size_t)Nq * Hq * 4);
    float* gi_all = (float*)alloc((size_t)Lq * Nq * H3q * 4);
    float* gh     = (float*)alloc((size_t)Nq * H3q * 4);
    float* prob   = (float*)alloc((size_t)Nq * Tq * 4);
    float* swp    = (float*)alloc((size_t)Nq * 4);
    float* partial= (float*)alloc((size_t)Nq * NPB * 4);
    float* eL     = (float*)alloc((size_t)Nq * Vq * 4);
    bf16*  embp   = (bf16*)alloc((size_t)NGV * NKT * 64 * 8 * 2);
    bf16*  wihp   = (bf16*)alloc((size_t)NGW * NKT * 64 * 8 * 2);
    bf16*  whhp   = (bf16*)alloc((size_t)NGW * NKT * 64 * 8 * 2);
    bf16*  encb   = (bf16*)alloc((size_t)Bq * Tq * Hq * 2);

    // ---- one-time prolog ----
    {
        int nf;
        nf = NGV * NKT * 64;  // 902400
        k_packf<<<dim3((nf + 255) / 256), dim3(256), 0, stream>>>(emb, embp, NGV, Vq);
        nf = NGW * NKT * 64;  // 60800
        k_packf<<<dim3((nf + 255) / 256), dim3(256), 0, stream>>>(w_ih, wihp, NGW, H3q);
        k_packf<<<dim3((nf + 255) / 256), dim3(256), 0, stream>>>(w_hh, whhp, NGW, H3q);
        const int n4 = (Bq * Tq * Hq) / 4;
        k_f2b4<<<dim3((n4 + 255) / 256), dim3(256), 0, stream>>>(enc, encb, n4);
        nf = Lq * NGH * NKT * 64;  // 240000
        k_xball<<<dim3((nf + 255) / 256), dim3(256), 0, stream>>>(
            slot_emb, dom, slo, emb, tgt, xbp, xlin);
        nf = NGH * NKT * 64;  // 24000
        k_h0<<<dim3((nf + 255) / 256), dim3(256), 0, stream>>>(ehid, h, hbp);
        k_gi_all<<<dim3(NGW, Lq), dim3(256), 0, stream>>>(xbp, wihp, gi_all);
        k_gh<<<dim3(NGW, 4), dim3(256), 0, stream>>>(hbp, whhp, gh);  // gh for step 0
    }

    // ---- decode loop: 3 kernels/step ----
    for (int step = 0; step < Lq; ++step) {
        k_attn<<<dim3(Nq), dim3(256), 0, stream>>>(
            gi_all, gh, b_ih, b_hh, h, hbp, xlin, encb, lens, w_ratio, b_ratio,
            w_gate, b_gate, prob, swp, out_gates, step);
        const int nb = NPB_USED + ((step + 1 < Lq) ? NGHB : 0);
        k_vocab_gh<<<dim3(nb), dim3(256), 0, stream>>>(
            hbp, embp, whhp, eL, partial, gh);
        k_final<<<dim3(Nq), dim3(512), 0, stream>>>(
            eL, prob, swp, partial, story, out, step);
    }
}